// Round 4
// baseline (511.937 us; speedup 1.0000x reference)
//
#include <hip/hip_runtime.h>
#include <hip/hip_bf16.h>
#include <math.h>

#define N 4096
#define D 128
#define EPSV 1e-8f
#define KS 8            // K-splits for gemm3; kRange = N/KS = 512

typedef __attribute__((ext_vector_type(8))) short bf16x8;
typedef __attribute__((ext_vector_type(4))) float f32x4;

__device__ __forceinline__ float lrelu(float x){ return x > 0.f ? x : 0.2f*x; }

__device__ __forceinline__ ushort bf16_hi(float x){
  __hip_bfloat16 h = __float2bfloat16(x);
  return *reinterpret_cast<ushort*>(&h);
}
__device__ __forceinline__ float bf16_tof(ushort u){
  __hip_bfloat16 h = *reinterpret_cast<__hip_bfloat16*>(&u);
  return __bfloat162float(h);
}

__device__ __forceinline__ float wave_sum(float v){
  #pragma unroll
  for (int off = 32; off; off >>= 1) v += __shfl_down(v, off);
  return v;
}
__device__ __forceinline__ float wave_max(float v){
  #pragma unroll
  for (int off = 32; off; off >>= 1) v = fmaxf(v, __shfl_down(v, off));
  return v;
}
__device__ __forceinline__ float block_sum256(float v, float* red){
  v = wave_sum(v);
  if ((threadIdx.x & 63) == 0) red[threadIdx.x >> 6] = v;
  __syncthreads();
  float r = (red[0] + red[1]) + (red[2] + red[3]);
  __syncthreads();
  return r;
}
__device__ __forceinline__ float block_max256(float v, float* red){
  v = wave_max(v);
  if ((threadIdx.x & 63) == 0) red[threadIdx.x >> 6] = v;
  __syncthreads();
  float r = fmaxf(fmaxf(red[0], red[1]), fmaxf(red[2], red[3]));
  __syncthreads();
  return r;
}

// dis[i] = 1/sqrt(sum_j adj[i][j] + 1e-8)
__global__ void k_rowsum(const float* __restrict__ adj, float* __restrict__ dis){
  int i = blockIdx.x;
  const float4* row = reinterpret_cast<const float4*>(adj + (size_t)i * N);
  float s = 0.f;
  #pragma unroll
  for (int l = 0; l < 4; ++l){
    float4 v = row[threadIdx.x + l * 256];
    s += (v.x + v.y) + (v.z + v.w);
  }
  __shared__ float red[4];
  s = block_sum256(s, red);
  if (threadIdx.x == 0) dis[i] = 1.0f / sqrtf(s + EPSV);
}

// u = h @ W (split to bf16 hi/lo); p = h @ a_src ; q = h @ a_dst
__global__ void k_uhat2(const float* __restrict__ h, const float* __restrict__ W,
                        const float* __restrict__ aa,
                        ushort* __restrict__ u_hi, ushort* __restrict__ u_lo,
                        float* __restrict__ p, float* __restrict__ q){
  int i = blockIdx.x, t = threadIdx.x;
  __shared__ float hs[D];
  __shared__ float red[4];
  float hv = h[(size_t)i * D + t];
  hs[t] = hv;
  __syncthreads();
  float acc = 0.f;
  #pragma unroll 8
  for (int k = 0; k < D; ++k) acc = fmaf(hs[k], W[k * D + t], acc);
  ushort hh = bf16_hi(acc);
  u_hi[(size_t)i * D + t] = hh;
  u_lo[(size_t)i * D + t] = bf16_hi(acc - bf16_tof(hh));
  float pv = hv * aa[t];
  float qv = hv * aa[D + t];
  pv = wave_sum(pv); qv = wave_sum(qv);
  if ((t & 63) == 0){ red[t >> 6] = pv; red[2 + (t >> 6)] = qv; }
  __syncthreads();
  if (t == 0){ p[i] = red[0] + red[1]; q[i] = red[2] + red[3]; }
}

// transpose u_hi/u_lo (4096x128) -> uT_hi/uT_lo (128x4096), 64-row tiles
__global__ void k_transposeU(const ushort* __restrict__ u_hi, const ushort* __restrict__ u_lo,
                             ushort* __restrict__ uT_hi, ushort* __restrict__ uT_lo){
  __shared__ ushort T[64][136];
  const int tid = threadIdx.x;
  const int j0 = blockIdx.x * 64;
  for (int pass = 0; pass < 2; ++pass){
    const ushort* s = pass ? u_lo : u_hi;
    ushort* d = pass ? uT_lo : uT_hi;
    __syncthreads();
    #pragma unroll
    for (int l = 0; l < 4; ++l){
      int r = l * 16 + (tid >> 4);
      int c = (tid & 15) * 8;
      *reinterpret_cast<uint4*>(&T[r][c]) =
          *reinterpret_cast<const uint4*>(s + (size_t)(j0 + r) * D + c);
    }
    __syncthreads();
    const int dd = tid >> 1, half = tid & 1;
    ushort* drow = d + (size_t)dd * N + j0 + half * 32;
    #pragma unroll
    for (int m4 = 0; m4 < 8; ++m4){
      ushort4 w;
      w.x = T[half * 32 + m4 * 4 + 0][dd];
      w.y = T[half * 32 + m4 * 4 + 1][dd];
      w.z = T[half * 32 + m4 * 4 + 2][dd];
      w.w = T[half * 32 + m4 * 4 + 3][dd];
      *reinterpret_cast<ushort4*>(drow + m4 * 4) = w;
    }
  }
}

// Row max + sum(exp) stats. MODE 0: src=adj with d_i d_j norm. MODE 1: src=b.
// MODE 2: src=b, plus attention-row stats from p,q.
template<int MODE>
__global__ void k_stats(const float* __restrict__ src, const float* __restrict__ dis,
                        const float* __restrict__ pv, const float* __restrict__ qv,
                        float* __restrict__ mb, float* __restrict__ lb,
                        float* __restrict__ ma, float* __restrict__ la){
  __shared__ float red[4];
  int i = blockIdx.x;
  const float4* src4 = reinterpret_cast<const float4*>(src + (size_t)i * N);
  const float4* dis4 = reinterpret_cast<const float4*>(dis);
  const float4* q4   = reinterpret_cast<const float4*>(qv);
  float di = (MODE == 0) ? dis[i] : 0.f;
  float pi = (MODE == 2) ? pv[i] : 0.f;
  float4 vals[4];
  float mx = -3.4e38f, amx = -3.4e38f;
  #pragma unroll
  for (int l = 0; l < 4; ++l){
    int t = threadIdx.x + l * 256;
    float4 a = src4[t];
    if (MODE == 0){
      float4 dj = dis4[t];
      a.x *= di * dj.x; a.y *= di * dj.y; a.z *= di * dj.z; a.w *= di * dj.w;
    }
    vals[l] = a;
    mx = fmaxf(mx, fmaxf(fmaxf(a.x, a.y), fmaxf(a.z, a.w)));
    if (MODE == 2){
      float4 qq = q4[t];
      float a0 = lrelu(pi + qq.x), a1 = lrelu(pi + qq.y);
      float a2 = lrelu(pi + qq.z), a3 = lrelu(pi + qq.w);
      amx = fmaxf(amx, fmaxf(fmaxf(a0, a1), fmaxf(a2, a3)));
    }
  }
  float m = block_max256(mx, red);
  float se = 0.f;
  #pragma unroll
  for (int l = 0; l < 4; ++l){
    float4 a = vals[l];
    se += expf(a.x - m) + expf(a.y - m) + expf(a.z - m) + expf(a.w - m);
  }
  float ls = block_sum256(se, red);
  if (MODE == 2){
    float am = block_max256(amx, red);
    float ase = 0.f;
    #pragma unroll
    for (int l = 0; l < 4; ++l){
      int t = threadIdx.x + l * 256;
      float4 qq = q4[t];
      ase += expf(lrelu(pi + qq.x) - am) + expf(lrelu(pi + qq.y) - am)
           + expf(lrelu(pi + qq.z) - am) + expf(lrelu(pi + qq.w) - am);
    }
    float al = block_sum256(ase, red);
    if (threadIdx.x == 0){ ma[i] = am; la[i] = al; }
  }
  if (threadIdx.x == 0){ mb[i] = m; lb[i] = ls; }
}

// ---------------------------------------------------------------------------
// MFMA gemm: s_part[y][i][n] = sum_{j in split y} weights(i,j) * u[j][n]
// Zero-LDS: A fragments built in-register from src rows (softmax on the fly,
// split-bf16 hi/lo, 3 MFMA per product); B fragments from uT_hi/uT_lo (L2).
// Block: 256 thr = 4 waves; wave owns 16 rows x 128 cols. grid = (64, KS).
// ---------------------------------------------------------------------------
template<int MODE>
__global__ __launch_bounds__(256, 2)
void k_gemm3(const float* __restrict__ src, const float* __restrict__ dis,
             const float* __restrict__ p, const float* __restrict__ q,
             const float* __restrict__ mbv, const float* __restrict__ lbv,
             const float* __restrict__ mav, const float* __restrict__ lav,
             const ushort* __restrict__ uT_hi, const ushort* __restrict__ uT_lo,
             float* __restrict__ s_part)
{
  const int lane = threadIdx.x & 63;
  const int wave = threadIdx.x >> 6;
  const int row0 = blockIdx.x * 64 + wave * 16;
  const int cl   = lane & 15;
  const int kgrp = (lane >> 4) * 8;
  const int arow = row0 + cl;
  const int k0b  = blockIdx.y * (N / KS);

  const float mrow = mbv[arow];
  const float rl   = 1.0f / lbv[arow];
  const float dif  = (MODE == 0) ? dis[arow] : 0.f;
  float pi = 0.f, mar = 0.f, rla = 0.f;
  if (MODE == 2){ pi = p[arow]; mar = mav[arow]; rla = 1.0f / lav[arow]; }

  const float* arow_ptr = src + (size_t)arow * N;

  f32x4 acc[8] = {};

  for (int kt = 0; kt < N / KS; kt += 32){
    const int kk = k0b + kt + kgrp;
    // B fragments (uT is 2 MB -> L2-resident)
    bf16x8 bh[8], bl[8];
    #pragma unroll
    for (int ct = 0; ct < 8; ++ct){
      size_t off = (size_t)(ct * 16 + cl) * N + kk;
      bh[ct] = *reinterpret_cast<const bf16x8*>(uT_hi + off);
      bl[ct] = *reinterpret_cast<const bf16x8*>(uT_lo + off);
    }
    // A: 8 fp32 from own row, softmax, split to bf16 hi/lo
    float av[8];
    *reinterpret_cast<float4*>(av)     = *reinterpret_cast<const float4*>(arow_ptr + kk);
    *reinterpret_cast<float4*>(av + 4) = *reinterpret_cast<const float4*>(arow_ptr + kk + 4);
    float ex[8];
    if (MODE == 0){
      float dv[8];
      *reinterpret_cast<float4*>(dv)     = *reinterpret_cast<const float4*>(dis + kk);
      *reinterpret_cast<float4*>(dv + 4) = *reinterpret_cast<const float4*>(dis + kk + 4);
      #pragma unroll
      for (int e = 0; e < 8; ++e) ex[e] = __expf(av[e] * dif * dv[e] - mrow) * rl;
    } else if (MODE == 1){
      #pragma unroll
      for (int e = 0; e < 8; ++e) ex[e] = __expf(av[e] - mrow) * rl;
    } else {
      float qv[8];
      *reinterpret_cast<float4*>(qv)     = *reinterpret_cast<const float4*>(q + kk);
      *reinterpret_cast<float4*>(qv + 4) = *reinterpret_cast<const float4*>(q + kk + 4);
      #pragma unroll
      for (int e = 0; e < 8; ++e){
        float c  = __expf(av[e] - mrow) * rl;
        float aw = __expf(lrelu(pi + qv[e]) - mar) * rla;
        ex[e] = 0.6f * c + 0.4f * aw;
      }
    }
    bf16x8 ahi, alo;
    #pragma unroll
    for (int e = 0; e < 8; ++e){
      ushort hh = bf16_hi(ex[e]);
      ahi[e] = (short)hh;
      alo[e] = (short)bf16_hi(ex[e] - bf16_tof(hh));
    }
    #pragma unroll
    for (int ct = 0; ct < 8; ++ct){
      acc[ct] = __builtin_amdgcn_mfma_f32_16x16x32_bf16(ahi, bh[ct], acc[ct], 0, 0, 0);
      acc[ct] = __builtin_amdgcn_mfma_f32_16x16x32_bf16(ahi, bl[ct], acc[ct], 0, 0, 0);
      acc[ct] = __builtin_amdgcn_mfma_f32_16x16x32_bf16(alo, bh[ct], acc[ct], 0, 0, 0);
    }
  }
  // epilogue: C/D layout col = lane&15, row = (lane>>4)*4 + reg
  const int orow = row0 + (lane >> 4) * 4;
  float* sp = s_part + ((size_t)blockIdx.y * N + orow) * D + cl;
  #pragma unroll
  for (int ct = 0; ct < 8; ++ct)
    #pragma unroll
    for (int r = 0; r < 4; ++r)
      sp[(size_t)r * D + ct * 16] = acc[ct][r];
}

// sum K-split partials + squash; FINAL -> fp32 out, else bf16 hi/lo v
template<bool FINAL>
__global__ void k_reduce_squash2(const float* __restrict__ s_part, float* __restrict__ out,
                                 ushort* __restrict__ vh, ushort* __restrict__ vl){
  int row = blockIdx.x, t = threadIdx.x;
  float a = 0.f;
  #pragma unroll
  for (int y = 0; y < KS; ++y) a += s_part[((size_t)y * N + row) * D + t];
  __shared__ float red[2];
  float ss = wave_sum(a * a);
  if ((t & 63) == 0) red[t >> 6] = ss;
  __syncthreads();
  float tot = red[0] + red[1];
  float n = sqrtf(tot);
  float f = n / ((1.0f + n) * (n + EPSV));
  float val = a * f;
  if (FINAL) out[(size_t)row * D + t] = val;
  else {
    ushort hh = bf16_hi(val);
    vh[(size_t)row * D + t] = hh;
    vl[(size_t)row * D + t] = bf16_hi(val - bf16_tof(hh));
  }
}

// ---------------------------------------------------------------------------
// b-update via MFMA: FIRST: b = d_i d_j adj + v@u^T ; else b += v@u^T
// Zero-LDS: A = v_hi/lo rows, B = u_hi/lo rows (both k-contiguous, L2-resident).
// Block 256 thr = 4 waves; wave owns 32 rows x 128 cols; tile 128x128; grid 1024.
// ---------------------------------------------------------------------------
template<bool FIRST>
__global__ __launch_bounds__(256, 4)
void k_bupd3(const ushort* __restrict__ v_hi, const ushort* __restrict__ v_lo,
             const ushort* __restrict__ u_hi, const ushort* __restrict__ u_lo,
             const float* __restrict__ adj, const float* __restrict__ dis,
             float* __restrict__ b)
{
  const int lane = threadIdx.x & 63;
  const int wave = threadIdx.x >> 6;
  const int row0 = (blockIdx.x >> 5) * 128 + wave * 32;
  const int col0 = (blockIdx.x & 31) * 128;
  const int cl   = lane & 15;
  const int kgrp = (lane >> 4) * 8;

  f32x4 acc[2][8] = {};

  #pragma unroll
  for (int ks = 0; ks < 4; ++ks){
    const int kk = ks * 32 + kgrp;
    bf16x8 a_h[2], a_l[2];
    #pragma unroll
    for (int rt = 0; rt < 2; ++rt){
      size_t off = (size_t)(row0 + rt * 16 + cl) * D + kk;
      a_h[rt] = *reinterpret_cast<const bf16x8*>(v_hi + off);
      a_l[rt] = *reinterpret_cast<const bf16x8*>(v_lo + off);
    }
    #pragma unroll
    for (int ct = 0; ct < 8; ++ct){
      size_t off = (size_t)(col0 + ct * 16 + cl) * D + kk;
      bf16x8 b_h = *reinterpret_cast<const bf16x8*>(u_hi + off);
      bf16x8 b_l = *reinterpret_cast<const bf16x8*>(u_lo + off);
      #pragma unroll
      for (int rt = 0; rt < 2; ++rt){
        acc[rt][ct] = __builtin_amdgcn_mfma_f32_16x16x32_bf16(a_h[rt], b_h, acc[rt][ct], 0, 0, 0);
        acc[rt][ct] = __builtin_amdgcn_mfma_f32_16x16x32_bf16(a_h[rt], b_l, acc[rt][ct], 0, 0, 0);
        acc[rt][ct] = __builtin_amdgcn_mfma_f32_16x16x32_bf16(a_l[rt], b_h, acc[rt][ct], 0, 0, 0);
      }
    }
  }

  float dcol[8];
  if (FIRST){
    #pragma unroll
    for (int ct = 0; ct < 8; ++ct) dcol[ct] = dis[col0 + ct * 16 + cl];
  }
  #pragma unroll
  for (int rt = 0; rt < 2; ++rt){
    const int orow = row0 + rt * 16 + (lane >> 4) * 4;
    #pragma unroll
    for (int r = 0; r < 4; ++r){
      const int gr = orow + r;
      const float drow = FIRST ? dis[gr] : 0.f;
      size_t base = (size_t)gr * N + col0 + cl;
      #pragma unroll
      for (int ct = 0; ct < 8; ++ct){
        size_t idx = base + ct * 16;
        if (FIRST) b[idx] = fmaf(adj[idx], drow * dcol[ct], acc[rt][ct][r]);
        else       b[idx] += acc[rt][ct][r];
      }
    }
  }
}

extern "C" void kernel_launch(void* const* d_in, const int* in_sizes, int n_in,
                              void* d_out, int out_size, void* d_ws, size_t ws_size,
                              hipStream_t stream) {
  const float* h   = (const float*)d_in[0];
  const float* adj = (const float*)d_in[1];
  const float* W   = (const float*)d_in[2];
  const float* aa  = (const float*)d_in[3];
  float* out = (float*)d_out;
  float* ws  = (float*)d_ws;

  float* dis = ws;                 // 4096
  float* p   = ws + 4096;
  float* q   = ws + 8192;
  float* mb  = ws + 12288;
  float* lb  = ws + 16384;
  float* ma  = ws + 20480;
  float* la  = ws + 24576;
  ushort* u_hi  = (ushort*)(ws + 32768);     // each 4096*128 ushort = 1 MB
  ushort* u_lo  = u_hi  + (size_t)N * D;
  ushort* uT_hi = u_lo  + (size_t)N * D;
  ushort* uT_lo = uT_hi + (size_t)N * D;
  ushort* v_hi  = uT_lo + (size_t)N * D;
  ushort* v_lo  = v_hi  + (size_t)N * D;
  float* b      = (float*)(v_lo + (size_t)N * D);   // 64 MB
  float* s_part = b + (size_t)N * N;                // KS * 2 MB = 16 MB

  dim3 gg(64, KS);

  k_rowsum<<<N, 256, 0, stream>>>(adj, dis);
  k_uhat2<<<N, 128, 0, stream>>>(h, W, aa, u_hi, u_lo, p, q);
  k_transposeU<<<64, 256, 0, stream>>>(u_hi, u_lo, uT_hi, uT_lo);

  // it 0: c1 = softmax(adj_norm); v1 = squash(c1 @ u)
  k_stats<0><<<N, 256, 0, stream>>>(adj, dis, p, q, mb, lb, ma, la);
  k_gemm3<0><<<gg, 256, 0, stream>>>(adj, dis, p, q, mb, lb, ma, la, uT_hi, uT_lo, s_part);
  k_reduce_squash2<false><<<N, 128, 0, stream>>>(s_part, out, v_hi, v_lo);
  // b1 = adj_norm + v1 @ u^T
  k_bupd3<true><<<1024, 256, 0, stream>>>(v_hi, v_lo, u_hi, u_lo, adj, dis, b);

  // it 1: c2 = softmax(b1); v2 = squash(c2 @ u)
  k_stats<1><<<N, 256, 0, stream>>>(b, dis, p, q, mb, lb, ma, la);
  k_gemm3<1><<<gg, 256, 0, stream>>>(b, dis, p, q, mb, lb, ma, la, uT_hi, uT_lo, s_part);
  k_reduce_squash2<false><<<N, 128, 0, stream>>>(s_part, out, v_hi, v_lo);
  // b2 = b1 + v2 @ u^T
  k_bupd3<false><<<1024, 256, 0, stream>>>(v_hi, v_lo, u_hi, u_lo, adj, dis, b);

  // it 2 + final: combined = 0.6*softmax(b2) + 0.4*softmax(attn); out = squash(combined @ u)
  k_stats<2><<<N, 256, 0, stream>>>(b, dis, p, q, mb, lb, ma, la);
  k_gemm3<2><<<gg, 256, 0, stream>>>(b, dis, p, q, mb, lb, ma, la, uT_hi, uT_lo, s_part);
  k_reduce_squash2<true><<<N, 128, 0, stream>>>(s_part, out, v_hi, v_lo);
}